// Round 7
// baseline (126.776 us; speedup 1.0000x reference)
//
#include <hip/hip_runtime.h>

#define BN_EPS 1e-5f
#define WW 56
#define HWSZ 3136      // 56*56
#define NB 32
#define CIN 240
#define MID 60
#define MIDG 20        // mid channels per group
#define COUT 240
#define COUTG 80
#define TH 7           // output rows per block (K_A)
#define THH 9          // TH + 2 halo rows

// ======== K_A: grouped conv1x1 (240->60) + BN1 + ReLU + depthwise 3x3 + BN2,
//   writing t2 channel-shuffled. Block = (b, group, 7-row tile), 512 threads.
//   Stage-1 x loads are batched 8-deep (8 float4 regs in flight per wave) and
//   go straight from global (L2/L3); only ONE barrier in the whole kernel.
//   LDS: mid 40,320 + w2s 720 + shB 80 = ~41.1 KB -> 3 blocks/CU (24 waves).
__global__ __launch_bounds__(512) void kA_conv1_dw(
        const float* __restrict__ x,
        const float* __restrict__ w1, const float* __restrict__ g1,
        const float* __restrict__ b1, const float* __restrict__ m1,
        const float* __restrict__ v1,
        const float* __restrict__ w2, const float* __restrict__ g2,
        const float* __restrict__ b2, const float* __restrict__ m2,
        const float* __restrict__ v2,
        float* __restrict__ t2) {
    __shared__ float mid[MIDG * THH * WW];   // conv1 output tile [20][9][56]
    __shared__ float w2s[MIDG * 9];
    __shared__ float shB[MIDG];

    const int tid = threadIdx.x;
    const int bid = blockIdx.x;
    const int t   = bid & 7;
    const int gb  = bid >> 3;
    const int g   = gb % 3;
    const int b   = gb / 3;
    const int h0  = t * TH;

    // prologue: scaled dw weights + BN2 shift (consumed after the single barrier)
    if (tid < MIDG * 9) {
        int chg = g * MIDG + tid / 9;
        w2s[tid] = w2[chg * 9 + tid % 9] * (g2[chg] * rsqrtf(v2[chg] + BN_EPS));
    }
    if (tid < MIDG) {
        int chg = g * MIDG + tid;
        float s2 = g2[chg] * rsqrtf(v2[chg] + BN_EPS);
        shB[tid] = b2[chg] - m2[chg] * s2;
    }

    const int q   = tid & 3;        // 5-channel quarter
    const int idx = tid >> 2;       // < 126 active
    const int r   = idx / 14, c4 = idx % 14;
    const bool act  = idx < 126;
    const int  hh   = h0 - 1 + r;
    const bool vrow = (hh >= 0 && hh < 56);

    // ---- stage 1: conv1x1, 5 out-channels per thread, 8-deep load batches ----
    float4 acc[5];
#pragma unroll
    for (int c = 0; c < 5; c++) acc[c] = make_float4(0.f, 0.f, 0.f, 0.f);

    if (act && vrow) {
        const float* xp = x + ((size_t)(b * CIN + g * 80)) * HWSZ + hh * WW + c4 * 4;
        const float* wrow = w1 + (size_t)(g * MIDG + q * 5) * 80;
#pragma unroll 2
        for (int step = 0; step < 10; ++step) {
            float4 xv0 = *(const float4*)(xp + (size_t)(step * 8 + 0) * HWSZ);
            float4 xv1 = *(const float4*)(xp + (size_t)(step * 8 + 1) * HWSZ);
            float4 xv2 = *(const float4*)(xp + (size_t)(step * 8 + 2) * HWSZ);
            float4 xv3 = *(const float4*)(xp + (size_t)(step * 8 + 3) * HWSZ);
            float4 xv4 = *(const float4*)(xp + (size_t)(step * 8 + 4) * HWSZ);
            float4 xv5 = *(const float4*)(xp + (size_t)(step * 8 + 5) * HWSZ);
            float4 xv6 = *(const float4*)(xp + (size_t)(step * 8 + 6) * HWSZ);
            float4 xv7 = *(const float4*)(xp + (size_t)(step * 8 + 7) * HWSZ);
#pragma unroll
            for (int c = 0; c < 5; c++) {
                float4 wa = *(const float4*)(wrow + c * 80 + step * 8);
                float4 wb = *(const float4*)(wrow + c * 80 + step * 8 + 4);
                acc[c].x += wa.x * xv0.x + wa.y * xv1.x + wa.z * xv2.x + wa.w * xv3.x
                          + wb.x * xv4.x + wb.y * xv5.x + wb.z * xv6.x + wb.w * xv7.x;
                acc[c].y += wa.x * xv0.y + wa.y * xv1.y + wa.z * xv2.y + wa.w * xv3.y
                          + wb.x * xv4.y + wb.y * xv5.y + wb.z * xv6.y + wb.w * xv7.y;
                acc[c].z += wa.x * xv0.z + wa.y * xv1.z + wa.z * xv2.z + wa.w * xv3.z
                          + wb.x * xv4.z + wb.y * xv5.z + wb.z * xv6.z + wb.w * xv7.z;
                acc[c].w += wa.x * xv0.w + wa.y * xv1.w + wa.z * xv2.w + wa.w * xv3.w
                          + wb.x * xv4.w + wb.y * xv5.w + wb.z * xv6.w + wb.w * xv7.w;
            }
        }
    }

    // ---- BN1 + ReLU -> mid ----
    if (act) {
#pragma unroll
        for (int c = 0; c < 5; c++) {
            int chg = g * MIDG + q * 5 + c;
            float s1v = g1[chg] * rsqrtf(v1[chg] + BN_EPS);
            float sh1v = b1[chg] - m1[chg] * s1v;
            float4 res = make_float4(0.f, 0.f, 0.f, 0.f);
            if (vrow) {
                res.x = fmaxf(acc[c].x * s1v + sh1v, 0.f);
                res.y = fmaxf(acc[c].y * s1v + sh1v, 0.f);
                res.z = fmaxf(acc[c].z * s1v + sh1v, 0.f);
                res.w = fmaxf(acc[c].w * s1v + sh1v, 0.f);
            }
            *(float4*)(mid + ((q * 5 + c) * THH + r) * WW + c4 * 4) = res;
        }
    }
    __syncthreads();   // the ONLY barrier

    // ---- depthwise 3x3 + BN2 -> t2 (channel-shuffled) ----
    // 20 ch x 7 rows x 14 quads = 1960 items
#pragma unroll
    for (int k = 0; k < 4; k++) {
        const int it = tid + k * 512;
        if (it < MIDG * 98) {
            const int ch = it / 98;
            const int pq = it % 98;
            const int r2 = pq / 14, cc = pq % 14;
            const float* base = mid + ch * (THH * WW);
            const float* kw = w2s + ch * 9;
            float4 a = make_float4(0.f, 0.f, 0.f, 0.f);
#pragma unroll
            for (int dy = 0; dy < 3; dy++) {
                const float* row = base + (r2 + dy) * WW + cc * 4;
                float4 m = *(const float4*)row;
                float l  = (cc > 0)  ? row[-1] : 0.f;
                float rt = (cc < 13) ? row[4]  : 0.f;
                const float k0 = kw[dy * 3 + 0];
                const float k1 = kw[dy * 3 + 1];
                const float k2 = kw[dy * 3 + 2];
                a.x += k0 * l   + k1 * m.x + k2 * m.y;
                a.y += k0 * m.x + k1 * m.y + k2 * m.z;
                a.z += k0 * m.y + k1 * m.z + k2 * m.w;
                a.w += k0 * m.z + k1 * m.w + k2 * rt;
            }
            const float s = shB[ch];
            a.x += s; a.y += s; a.z += s; a.w += s;
            const int jj = ch * 3 + g;   // shuffled: S[ci*3+g] = mid_group_g[ci]
            *(float4*)(t2 + ((size_t)(b * MID + jj)) * HWSZ + (h0 + r2) * WW + cc * 4) = a;
        }
    }
}

// ======== K_B: grouped conv1x1 (60->240, inputs pre-shuffled) + BN3 + ReLU
//          + residual add. One thread: one float4 of positions, 20 out-channels
//          (q = item&3 -> lanes 0-3 share t2 loads, dedup'd in the coalescer).
__global__ __launch_bounds__(256) void kB_conv3_res(
        const float* __restrict__ t2, const float* __restrict__ w3,
        const float* __restrict__ g3, const float* __restrict__ b3,
        const float* __restrict__ m3, const float* __restrict__ v3,
        const float* __restrict__ x, float* __restrict__ out) {
    __shared__ float wT[3 * MIDG * COUTG];  // [g][ci][cg] : 4800 floats
    __shared__ float s3[COUT], sh3[COUT];
    const int tid = threadIdx.x;
    for (int i = tid; i < 3 * MIDG * COUTG; i += 256) {
        int co_glob = i / MIDG;     // row of w3
        int ci = i % MIDG;
        int gg = co_glob / COUTG;
        int cg = co_glob % COUTG;
        wT[(gg * MIDG + ci) * COUTG + cg] = w3[i];
    }
    if (tid < COUT) {
        float inv = g3[tid] * rsqrtf(v3[tid] + BN_EPS);
        s3[tid] = inv;
        sh3[tid] = b3[tid] - m3[tid] * inv;
    }
    __syncthreads();

    const int item = blockIdx.x * 256 + tid;  // < 301056
    const unsigned q  = (unsigned)item & 3u;  // out-channel quarter
    const unsigned pg = (unsigned)item >> 2;
    const unsigned p4 = pg % 784u;
    const unsigned bg = pg / 784u;
    const unsigned b = bg / 3u, g = bg % 3u;
    const int pos = (int)p4 * 4;

    float4 acc[MIDG];
#pragma unroll
    for (int c = 0; c < MIDG; c++) acc[c] = make_float4(0.f, 0.f, 0.f, 0.f);

    const float4* wl4 = (const float4*)wT;
#pragma unroll 4
    for (int ci = 0; ci < MIDG; ci++) {
        int csh = (int)g * MIDG + ci;          // t2 pre-shuffled: read linearly
        float4 xv = *(const float4*)(t2 + ((size_t)(b * MID + csh)) * HWSZ + pos);
        int wbase = (csh * COUTG + q * MIDG) / 4;  // float4 index
#pragma unroll
        for (int k4 = 0; k4 < 5; k4++) {
            float4 wv = wl4[wbase + k4];
            acc[k4 * 4 + 0].x += wv.x * xv.x; acc[k4 * 4 + 0].y += wv.x * xv.y;
            acc[k4 * 4 + 0].z += wv.x * xv.z; acc[k4 * 4 + 0].w += wv.x * xv.w;
            acc[k4 * 4 + 1].x += wv.y * xv.x; acc[k4 * 4 + 1].y += wv.y * xv.y;
            acc[k4 * 4 + 1].z += wv.y * xv.z; acc[k4 * 4 + 1].w += wv.y * xv.w;
            acc[k4 * 4 + 2].x += wv.z * xv.x; acc[k4 * 4 + 2].y += wv.z * xv.y;
            acc[k4 * 4 + 2].z += wv.z * xv.z; acc[k4 * 4 + 2].w += wv.z * xv.w;
            acc[k4 * 4 + 3].x += wv.w * xv.x; acc[k4 * 4 + 3].y += wv.w * xv.y;
            acc[k4 * 4 + 3].z += wv.w * xv.z; acc[k4 * 4 + 3].w += wv.w * xv.w;
        }
    }

#pragma unroll
    for (int co = 0; co < MIDG; co++) {
        int cg = (int)g * COUTG + (int)q * MIDG + co;
        float sc = s3[cg], sf = sh3[cg];
        float4 xr = *(const float4*)(x + ((size_t)(b * CIN + cg)) * HWSZ + pos);
        float4 o;
        o.x = fmaxf(acc[co].x * sc + sf, 0.f) + xr.x;
        o.y = fmaxf(acc[co].y * sc + sf, 0.f) + xr.y;
        o.z = fmaxf(acc[co].z * sc + sf, 0.f) + xr.z;
        o.w = fmaxf(acc[co].w * sc + sf, 0.f) + xr.w;
        *(float4*)(out + ((size_t)(b * CIN + cg)) * HWSZ + pos) = o;
    }
}

extern "C" void kernel_launch(void* const* d_in, const int* in_sizes, int n_in,
                              void* d_out, int out_size, void* d_ws, size_t ws_size,
                              hipStream_t stream) {
    const float* x  = (const float*)d_in[0];
    const float* w1 = (const float*)d_in[1];
    const float* g1 = (const float*)d_in[2];
    const float* b1 = (const float*)d_in[3];
    const float* m1 = (const float*)d_in[4];
    const float* v1 = (const float*)d_in[5];
    const float* w2 = (const float*)d_in[6];
    const float* g2 = (const float*)d_in[7];
    const float* b2 = (const float*)d_in[8];
    const float* m2 = (const float*)d_in[9];
    const float* v2 = (const float*)d_in[10];
    const float* w3 = (const float*)d_in[11];
    const float* g3 = (const float*)d_in[12];
    const float* b3 = (const float*)d_in[13];
    const float* m3 = (const float*)d_in[14];
    const float* v3 = (const float*)d_in[15];
    float* out = (float*)d_out;

    float* t2 = (float*)d_ws;   // 32*60*3136 floats = 24 MB (shuffled dw output)

    // K_A: 32 b * 3 g * 8 tiles = 768 blocks = exactly 3 per CU
    kA_conv1_dw<<<768, 512, 0, stream>>>(x, w1, g1, b1, m1, v1,
                                         w2, g2, b2, m2, v2, t2);
    // K_B: 301056 threads / 256 = 1176 blocks
    kB_conv3_res<<<1176, 256, 0, stream>>>(t2, w3, g3, b3, m3, v3, x, out);
}

// Round 8
// 86.996 us; speedup vs baseline: 1.4573x; 1.4573x over previous
//
#include <hip/hip_runtime.h>

#define BN_EPS 1e-5f
#define WW 56
#define HWSZ 3136      // 56*56
#define NB 32
#define CIN 240
#define MID 60
#define MIDG 20        // mid channels per group
#define COUT 240
#define COUTG 80
#define TH 7           // output rows per block
#define THH 9          // TH + 2 halo rows

// ======== K_A: grouped conv1x1 (240->60) + BN1 + ReLU + depthwise 3x3 + BN2,
//   writing t2 channel-shuffled.
//   Block = (cb2, b, g, 7-row tile): 10 mid-channels per block, 256 threads.
//   Grid 2*32*3*8 = 1536 = exactly 6 blocks/CU; LDS ~24 KB -> 6 resident.
//   cb2 is the HIGH grid bit so the two blocks sharing an x-tile are 768 apart
//   -> same XCD slot -> shared L2 for x.
//   conv1: weights from LDS (lgkm queue), x batched 8-deep in vmcnt queue.
__global__ __launch_bounds__(256) void kA_conv1_dw(
        const float* __restrict__ x,
        const float* __restrict__ w1, const float* __restrict__ g1,
        const float* __restrict__ b1, const float* __restrict__ m1,
        const float* __restrict__ v1,
        const float* __restrict__ w2, const float* __restrict__ g2,
        const float* __restrict__ b2, const float* __restrict__ m2,
        const float* __restrict__ v2,
        float* __restrict__ t2) {
    __shared__ float mid[10 * THH * WW];   // [10][9][56] = 20,160 B
    __shared__ float w1s[10 * 80];         // scale-folded conv1 weights, 3,200 B
    __shared__ float w2s[10 * 9];          // scale-folded dw weights
    __shared__ float shA[10], shB[10];

    const int tid  = threadIdx.x;
    const int bid  = blockIdx.x;
    const int cb2  = bid >> 9;             // 0/1: which 10-channel half (high bit, 768 apart)
    const int rest = bid & 511;            // not 511... grid half is 768; use explicit math
    // NOTE: 768 is not a power of two; decompose explicitly:
    const int cb2x = (bid >= 768) ? 1 : 0;
    const int r768 = bid - cb2x * 768;
    const int t    = r768 & 7;
    const int gb   = r768 >> 3;
    const int g    = gb % 3;
    const int b    = gb / 3;
    const int h0   = t * TH;
    (void)cb2; (void)rest;

    const int ch0 = g * MIDG + cb2x * 10;  // first of this block's 10 mid-channels

    // ---- stage weights (scale-folded) ----
    for (int i = tid; i < 800; i += 256) {
        int cl = i / 80;
        int chg = ch0 + cl;
        w1s[i] = w1[chg * 80 + i % 80] * (g1[chg] * rsqrtf(v1[chg] + BN_EPS));
    }
    if (tid < 90) {
        int cl = tid / 9;
        int chg = ch0 + cl;
        w2s[tid] = w2[chg * 9 + tid % 9] * (g2[chg] * rsqrtf(v2[chg] + BN_EPS));
    }
    if (tid < 10) {
        int chg = ch0 + tid;
        float s1v = g1[chg] * rsqrtf(v1[chg] + BN_EPS);
        shA[tid] = b1[chg] - m1[chg] * s1v;
        float s2v = g2[chg] * rsqrtf(v2[chg] + BN_EPS);
        shB[tid] = b2[chg] - m2[chg] * s2v;
    }
    __syncthreads();

    // ---- stage 1: conv1x1, 5 out-channels x 1 quad per thread ----
    // cb = tid&1 (5-ch sub-batch), idx = tid>>1 < 126 -> (r, c4)
    const int cb  = tid & 1;
    const int idx = tid >> 1;
    const int r   = idx / 14, c4 = idx % 14;
    const bool act  = idx < 126;
    const int  hh   = h0 - 1 + r;
    const bool vrow = (hh >= 0 && hh < 56);

    float4 acc[5];
#pragma unroll
    for (int c = 0; c < 5; c++) acc[c] = make_float4(0.f, 0.f, 0.f, 0.f);

    if (act && vrow) {
        const float* xp = x + ((size_t)(b * CIN + g * 80)) * HWSZ + hh * WW + c4 * 4;
        const float4* w4 = (const float4*)w1s;   // [cl][ci4] : [10][20]
        for (int s8 = 0; s8 < 10; ++s8) {        // 8 input channels per step
            float4 xv0 = *(const float4*)(xp + (size_t)(s8 * 8 + 0) * HWSZ);
            float4 xv1 = *(const float4*)(xp + (size_t)(s8 * 8 + 1) * HWSZ);
            float4 xv2 = *(const float4*)(xp + (size_t)(s8 * 8 + 2) * HWSZ);
            float4 xv3 = *(const float4*)(xp + (size_t)(s8 * 8 + 3) * HWSZ);
            float4 xv4 = *(const float4*)(xp + (size_t)(s8 * 8 + 4) * HWSZ);
            float4 xv5 = *(const float4*)(xp + (size_t)(s8 * 8 + 5) * HWSZ);
            float4 xv6 = *(const float4*)(xp + (size_t)(s8 * 8 + 6) * HWSZ);
            float4 xv7 = *(const float4*)(xp + (size_t)(s8 * 8 + 7) * HWSZ);
#pragma unroll
            for (int c = 0; c < 5; c++) {
                const int cl = cb * 5 + c;
                float4 wa = w4[cl * 20 + s8 * 2];
                float4 wb = w4[cl * 20 + s8 * 2 + 1];
                acc[c].x += wa.x * xv0.x + wa.y * xv1.x + wa.z * xv2.x + wa.w * xv3.x
                          + wb.x * xv4.x + wb.y * xv5.x + wb.z * xv6.x + wb.w * xv7.x;
                acc[c].y += wa.x * xv0.y + wa.y * xv1.y + wa.z * xv2.y + wa.w * xv3.y
                          + wb.x * xv4.y + wb.y * xv5.y + wb.z * xv6.y + wb.w * xv7.y;
                acc[c].z += wa.x * xv0.z + wa.y * xv1.z + wa.z * xv2.z + wa.w * xv3.z
                          + wb.x * xv4.z + wb.y * xv5.z + wb.z * xv6.z + wb.w * xv7.z;
                acc[c].w += wa.x * xv0.w + wa.y * xv1.w + wa.z * xv2.w + wa.w * xv3.w
                          + wb.x * xv4.w + wb.y * xv5.w + wb.z * xv6.w + wb.w * xv7.w;
            }
        }
    }

    // ---- BN1 shift + ReLU -> mid ----
    if (act) {
#pragma unroll
        for (int c = 0; c < 5; c++) {
            const int cl = cb * 5 + c;
            float4 res = make_float4(0.f, 0.f, 0.f, 0.f);
            if (vrow) {
                float s = shA[cl];
                res.x = fmaxf(acc[c].x + s, 0.f);
                res.y = fmaxf(acc[c].y + s, 0.f);
                res.z = fmaxf(acc[c].z + s, 0.f);
                res.w = fmaxf(acc[c].w + s, 0.f);
            }
            *(float4*)(mid + (cl * THH + r) * WW + c4 * 4) = res;
        }
    }
    __syncthreads();

    // ---- depthwise 3x3 + BN2 -> t2 (channel-shuffled) ----
    // 10 ch x 7 rows x 14 quads = 980 items
#pragma unroll
    for (int k = 0; k < 4; k++) {
        const int it = tid + k * 256;
        if (it < 980) {
            const int cl = it / 98;
            const int pq = it % 98;
            const int r2 = pq / 14, cc = pq % 14;
            const float* base = mid + cl * (THH * WW);
            const float* kw = w2s + cl * 9;
            float4 a = make_float4(0.f, 0.f, 0.f, 0.f);
#pragma unroll
            for (int dy = 0; dy < 3; dy++) {
                const float* row = base + (r2 + dy) * WW + cc * 4;
                float4 m = *(const float4*)row;
                float l  = (cc > 0)  ? row[-1] : 0.f;
                float rt = (cc < 13) ? row[4]  : 0.f;
                const float k0 = kw[dy * 3 + 0];
                const float k1 = kw[dy * 3 + 1];
                const float k2 = kw[dy * 3 + 2];
                a.x += k0 * l   + k1 * m.x + k2 * m.y;
                a.y += k0 * m.x + k1 * m.y + k2 * m.z;
                a.z += k0 * m.y + k1 * m.z + k2 * m.w;
                a.w += k0 * m.z + k1 * m.w + k2 * rt;
            }
            const float s = shB[cl];
            a.x += s; a.y += s; a.z += s; a.w += s;
            const int ci_in_group = cb2x * 10 + cl;           // [0,20)
            const int jj = ci_in_group * 3 + g;               // shuffled channel
            *(float4*)(t2 + ((size_t)(b * MID + jj)) * HWSZ + (h0 + r2) * WW + cc * 4) = a;
        }
    }
}

// ======== K_B: grouped conv1x1 (60->240, inputs pre-shuffled) + BN3 + ReLU
//          + residual add. One thread: one float4 of positions, 20 out-channels
//          (q = item&3 -> lanes 0-3 share t2 loads, dedup'd in the coalescer).
__global__ __launch_bounds__(256) void kB_conv3_res(
        const float* __restrict__ t2, const float* __restrict__ w3,
        const float* __restrict__ g3, const float* __restrict__ b3,
        const float* __restrict__ m3, const float* __restrict__ v3,
        const float* __restrict__ x, float* __restrict__ out) {
    __shared__ float wT[3 * MIDG * COUTG];  // [g][ci][cg] : 4800 floats
    __shared__ float s3[COUT], sh3[COUT];
    const int tid = threadIdx.x;
    for (int i = tid; i < 3 * MIDG * COUTG; i += 256) {
        int co_glob = i / MIDG;     // row of w3
        int ci = i % MIDG;
        int gg = co_glob / COUTG;
        int cg = co_glob % COUTG;
        wT[(gg * MIDG + ci) * COUTG + cg] = w3[i];
    }
    if (tid < COUT) {
        float inv = g3[tid] * rsqrtf(v3[tid] + BN_EPS);
        s3[tid] = inv;
        sh3[tid] = b3[tid] - m3[tid] * inv;
    }
    __syncthreads();

    const int item = blockIdx.x * 256 + tid;  // < 301056
    const unsigned q  = (unsigned)item & 3u;  // out-channel quarter
    const unsigned pg = (unsigned)item >> 2;
    const unsigned p4 = pg % 784u;
    const unsigned bg = pg / 784u;
    const unsigned b = bg / 3u, g = bg % 3u;
    const int pos = (int)p4 * 4;

    float4 acc[MIDG];
#pragma unroll
    for (int c = 0; c < MIDG; c++) acc[c] = make_float4(0.f, 0.f, 0.f, 0.f);

    const float4* wl4 = (const float4*)wT;
#pragma unroll 4
    for (int ci = 0; ci < MIDG; ci++) {
        int csh = (int)g * MIDG + ci;          // t2 pre-shuffled: read linearly
        float4 xv = *(const float4*)(t2 + ((size_t)(b * MID + csh)) * HWSZ + pos);
        int wbase = (csh * COUTG + q * MIDG) / 4;  // float4 index
#pragma unroll
        for (int k4 = 0; k4 < 5; k4++) {
            float4 wv = wl4[wbase + k4];
            acc[k4 * 4 + 0].x += wv.x * xv.x; acc[k4 * 4 + 0].y += wv.x * xv.y;
            acc[k4 * 4 + 0].z += wv.x * xv.z; acc[k4 * 4 + 0].w += wv.x * xv.w;
            acc[k4 * 4 + 1].x += wv.y * xv.x; acc[k4 * 4 + 1].y += wv.y * xv.y;
            acc[k4 * 4 + 1].z += wv.y * xv.z; acc[k4 * 4 + 1].w += wv.y * xv.w;
            acc[k4 * 4 + 2].x += wv.z * xv.x; acc[k4 * 4 + 2].y += wv.z * xv.y;
            acc[k4 * 4 + 2].z += wv.z * xv.z; acc[k4 * 4 + 2].w += wv.z * xv.w;
            acc[k4 * 4 + 3].x += wv.w * xv.x; acc[k4 * 4 + 3].y += wv.w * xv.y;
            acc[k4 * 4 + 3].z += wv.w * xv.z; acc[k4 * 4 + 3].w += wv.w * xv.w;
        }
    }

#pragma unroll
    for (int co = 0; co < MIDG; co++) {
        int cg = (int)g * COUTG + (int)q * MIDG + co;
        float sc = s3[cg], sf = sh3[cg];
        float4 xr = *(const float4*)(x + ((size_t)(b * CIN + cg)) * HWSZ + pos);
        float4 o;
        o.x = fmaxf(acc[co].x * sc + sf, 0.f) + xr.x;
        o.y = fmaxf(acc[co].y * sc + sf, 0.f) + xr.y;
        o.z = fmaxf(acc[co].z * sc + sf, 0.f) + xr.z;
        o.w = fmaxf(acc[co].w * sc + sf, 0.f) + xr.w;
        *(float4*)(out + ((size_t)(b * CIN + cg)) * HWSZ + pos) = o;
    }
}

extern "C" void kernel_launch(void* const* d_in, const int* in_sizes, int n_in,
                              void* d_out, int out_size, void* d_ws, size_t ws_size,
                              hipStream_t stream) {
    const float* x  = (const float*)d_in[0];
    const float* w1 = (const float*)d_in[1];
    const float* g1 = (const float*)d_in[2];
    const float* b1 = (const float*)d_in[3];
    const float* m1 = (const float*)d_in[4];
    const float* v1 = (const float*)d_in[5];
    const float* w2 = (const float*)d_in[6];
    const float* g2 = (const float*)d_in[7];
    const float* b2 = (const float*)d_in[8];
    const float* m2 = (const float*)d_in[9];
    const float* v2 = (const float*)d_in[10];
    const float* w3 = (const float*)d_in[11];
    const float* g3 = (const float*)d_in[12];
    const float* b3 = (const float*)d_in[13];
    const float* m3 = (const float*)d_in[14];
    const float* v3 = (const float*)d_in[15];
    float* out = (float*)d_out;

    float* t2 = (float*)d_ws;   // 32*60*3136 floats = 24 MB (shuffled dw output)

    // K_A: 2 halves * 32 b * 3 g * 8 tiles = 1536 blocks = exactly 6 per CU
    kA_conv1_dw<<<1536, 256, 0, stream>>>(x, w1, g1, b1, m1, v1,
                                          w2, g2, b2, m2, v2, t2);
    // K_B: 301056 threads / 256 = 1176 blocks
    kB_conv3_res<<<1176, 256, 0, stream>>>(t2, w3, g3, b3, m3, v3, x, out);
}